// Round 10
// baseline (219.873 us; speedup 1.0000x reference)
//
#include <hip/hip_runtime.h>

#define BS   8
#define NCH  7
#define PX   409600      // 640*640
#define NBIN 65536
#define NCHK 256
#define EPSF 1e-6f
#define NT   256
#define GXM  50          // blocks per (batch,half); GXM*NT*ITM == PX/4
#define ITM  8

__device__ __forceinline__ float sigf(float x) {
    return 1.0f / (1.0f + __expf(-x));
}

__device__ __forceinline__ unsigned wred_u(unsigned v) {
    #pragma unroll
    for (int o = 32; o; o >>= 1) v += __shfl_down(v, o);
    return v;
}

// interleaved 3-value wave reduction: independent chains overlap ds-permute latency
__device__ __forceinline__ void wred3_f(float& v0, float& v1, float& v2) {
    #pragma unroll
    for (int o = 32; o; o >>= 1) {
        float t0 = __shfl_down(v0, o);
        float t1 = __shfl_down(v1, o);
        float t2 = __shfl_down(v2, o);
        v0 += t0; v1 += t1; v2 += t2;
    }
}

// =====================================================================================
// two-level coalesced select over chunks[256] / bins[65536] (rare path only)
// =====================================================================================
__device__ void select2(const unsigned* __restrict__ chunks,
                        const unsigned* __restrict__ bins,
                        unsigned k, unsigned* out_bin, unsigned* out_rank) {
    __shared__ unsigned cs[256];
    int t = threadIdx.x;
    cs[t] = chunks[t];
    __syncthreads();
    #pragma unroll
    for (int off = 1; off < 256; off <<= 1) {
        unsigned v = cs[t];
        unsigned a = (t + off < 256) ? cs[t + off] : 0u;
        __syncthreads();
        cs[t] = v + a;
        __syncthreads();
    }
    {
        unsigned sfx  = cs[t];
        unsigned sfx1 = (t < 255) ? cs[t + 1] : 0u;
        if (sfx >= k && sfx1 < k) { *out_bin = (unsigned)t; *out_rank = k - sfx1; }
    }
    __syncthreads();
    unsigned chunk = *out_bin, krem = *out_rank;
    cs[t] = bins[chunk * 256 + t];
    __syncthreads();
    #pragma unroll
    for (int off = 1; off < 256; off <<= 1) {
        unsigned v = cs[t];
        unsigned a = (t + off < 256) ? cs[t + off] : 0u;
        __syncthreads();
        cs[t] = v + a;
        __syncthreads();
    }
    {
        unsigned sfx  = cs[t];
        unsigned sfx1 = (t < 255) ? cs[t + 1] : 0u;
        if (sfx >= krem && sfx1 < krem) {
            *out_bin  = chunk * 256 + (unsigned)t;
            *out_rank = krem - sfx1;
        }
    }
    __syncthreads();
}

// =====================================================================================
// k_main: one block per (batch, half, slab). half selects channels {0,1,2} or {3,4,5};
// p6/mask re-read 2x per batch (round 7 re-read them 6x -> 327MB logical; now 222MB).
// Round-7-proven construct: per iteration, ONE load cluster (8-9 dwordx4) pinned by a
// single sched_barrier(0), then straight-line compute. No ballot, no double-buffer
// (rounds 8/9's macro double-buffer + ballot construct core-dumped twice -> abandoned).
// half==0 blocks also produce pos/zero counts and the 3 speculative (M=1) L_c sums.
// =====================================================================================
__global__ __launch_bounds__(256) void k_main(
        const float* __restrict__ preds, const int* __restrict__ labels,
        const int* __restrict__ mask,
        float* __restrict__ psumA,           // [BS][3][GXM]  (half==0 blocks)
        unsigned* __restrict__ ppos,         // [BS][GXM]
        unsigned* __restrict__ pzero,        // [BS][GXM]
        float* __restrict__ psumB,           // [BS*6][3][GXM]
        unsigned* __restrict__ done) {
    const int tid = threadIdx.x;
    const int y = blockIdx.y;                // b*2 + half
    const int b = y >> 1, half = y & 1;
    const int cbase = half * 3;
    const int cb = blockIdx.x;
    const bool h0 = (half == 0);
    if (y == 0 && cb == 0 && tid == 0) *done = 0u;   // re-arm k_sel ticket

    const float* p6  = preds + ((size_t)b * NCH + 6) * PX;
    const int*   l6  = labels + ((size_t)b * NCH + 6) * PX;
    const int*   mk  = mask + (size_t)b * PX;
    const float* pc0 = preds + ((size_t)b * NCH + cbase) * PX;
    const int*   lc0 = labels + ((size_t)b * NCH + cbase) * PX;

    float sn[3] = {0.f, 0.f, 0.f}, sp[3] = {0.f, 0.f, 0.f};
    unsigned sl[3] = {0u, 0u, 0u};
    float a0 = 0.f, a1 = 0.f;
    unsigned a2c = 0, cnt = 0;               // cnt = pos | (zero<<16)

    for (int it = 0; it < ITM; ++it) {
        const int g  = cb * (NT * ITM) + it * NT + tid;
        const int px = g * 4;
        // ---- load cluster: 8 (9 for half0) dwordx4, pinned above compute ----
        float4 P6 = *(const float4*)(p6 + px);
        int4   M  = *(const int4*)(mk + px);
        int4   L6 = make_int4(0, 0, 0, 0);
        if (h0) L6 = *(const int4*)(l6 + px);
        float4 P[3]; int4 L[3];
        #pragma unroll
        for (int c = 0; c < 3; c++) {
            P[c] = *(const float4*)(pc0 + (size_t)c * PX + px);
            L[c] = *(const int4*)(lc0 + (size_t)c * PX + px);
        }
        __builtin_amdgcn_sched_barrier(0);   // loads stay issued above this line

        float mm[4]  = {(float)M.x, (float)M.y, (float)M.z, (float)M.w};
        float p6a[4] = {P6.x, P6.y, P6.z, P6.w};
        int   l6a[4] = {L6.x, L6.y, L6.z, L6.w};
        #pragma unroll
        for (int v = 0; v < 4; v++) {
            float pn = sigf(p6a[v]) * mm[v];
            bool W   = (pn >= 0.5f);
            if (h0) {
                cnt += W ? 1u : (__float_as_uint(pn) == 0u ? 0x10000u : 0u);
                bool ln = (l6a[v] != 0) && (mm[v] != 0.0f);
                a0 += ln ? pn : 0.0f;        // spec a0 = sum pn*ln  (M=1)
                a1 += pn * pn;               // spec a1 = sum pn^2
                a2c += ln ? 1u : 0u;         // spec a2 = sum ln
            }
            float pv[3] = {((const float*)&P[0])[v], ((const float*)&P[1])[v],
                           ((const float*)&P[2])[v]};
            int   lv[3] = {((const int*)&L[0])[v], ((const int*)&L[1])[v],
                           ((const int*)&L[2])[v]};
            #pragma unroll
            for (int c = 0; c < 3; c++) {
                float s = sigf(pv[c]);
                bool lw = W && (lv[c] != 0);
                sn[c] += lw ? s : 0.0f;      // sum S*G*W
                sp[c] += W ? s * s : 0.0f;   // sum S*S*W
                sl[c] += lw ? 1u : 0u;       // sum G*G*W (G in {0,1})
            }
        }
    }

    // ---- block reduce ----
    __shared__ float red[4][3][3];
    __shared__ float redA[4][3];
    __shared__ unsigned redC[4];
    const int lane = tid & 63, wid = tid >> 6;
    #pragma unroll
    for (int c = 0; c < 3; c++) {
        float v0 = sn[c], v1 = sp[c], v2 = (float)sl[c];
        wred3_f(v0, v1, v2);
        if (lane == 0) { red[wid][c][0] = v0; red[wid][c][1] = v1; red[wid][c][2] = v2; }
    }
    if (h0) {
        float u0 = a0, u1 = a1, u2 = (float)a2c;
        wred3_f(u0, u1, u2);
        unsigned cr = wred_u(cnt);
        if (lane == 0) { redA[wid][0] = u0; redA[wid][1] = u1; redA[wid][2] = u2; redC[wid] = cr; }
    }
    __syncthreads();
    if (tid < 9) {
        int c = tid / 3, j = tid % 3;
        float tot = red[0][c][j] + red[1][c][j] + red[2][c][j] + red[3][c][j];
        psumB[((size_t)(b * 6 + cbase + c) * 3 + j) * GXM + cb] = tot;
    }
    if (h0) {
        if (tid >= 9 && tid < 12) {
            int j = tid - 9;
            float tot = redA[0][j] + redA[1][j] + redA[2][j] + redA[3][j];
            psumA[((size_t)b * 3 + j) * GXM + cb] = tot;
        }
        if (tid == 12) {
            unsigned ct = redC[0] + redC[1] + redC[2] + redC[3];
            ppos[b * GXM + cb]  = ct & 0xFFFFu;
            pzero[b * GXM + cb] = ct >> 16;
        }
    }
}

// =====================================================================================
// k_sel: 8 blocks, one per batch. Reduce partials; fast path (always hit on bench
// data): thr<=0 or k >= nonzero-negatives -> speculative sums exact. Rare path: solo
// exact selection + rescan. 8-block ticket emits final losses.
// =====================================================================================
__global__ __launch_bounds__(256) void k_sel(
        const float* __restrict__ preds, const int* __restrict__ labels,
        const int* __restrict__ mask,
        const float* __restrict__ psumA, const float* __restrict__ psumB,
        const unsigned* __restrict__ ppos, const unsigned* __restrict__ pzero,
        unsigned* __restrict__ histws, unsigned* __restrict__ chunkws,
        float* __restrict__ lcls, unsigned* __restrict__ done,
        float* __restrict__ out) {
    const int tid = threadIdx.x;
    const int b = blockIdx.x;
    const int lane = tid & 63, wid = tid >> 6;

    // ---- reduce counts + 21 sums into LDS ----
    __shared__ float S[21];
    __shared__ unsigned C[2];
    if (tid < 21) S[tid] = 0.f;
    if (tid < 2) C[tid] = 0u;
    __syncthreads();
    {
        unsigned pc = 0, zc = 0;
        for (int i = tid; i < GXM; i += NT) {
            pc += ppos[b * GXM + i];
            zc += pzero[b * GXM + i];
        }
        pc = wred_u(pc); zc = wred_u(zc);
        if (lane == 0) { atomicAdd(&C[0], pc); atomicAdd(&C[1], zc); }
    }
    for (int i = tid; i < 3 * GXM; i += NT)
        atomicAdd(&S[18 + i / GXM], psumA[(size_t)b * 3 * GXM + i]);
    for (int i = tid; i < 6 * 3 * GXM; i += NT) {
        int cch = i / (3 * GXM);
        int j   = (i / GXM) % 3;
        atomicAdd(&S[j * 6 + cch], psumB[(size_t)b * 6 * 3 * GXM + i]);
    }
    __syncthreads();
    const unsigned np = C[0], zc = C[1];

    const unsigned k = np * 3u;
    const bool active = ((unsigned)PX - np > k) && (k > 0u);
    const unsigned nzneg = (unsigned)PX - np - zc;   // negatives with pn > 0

    float Lc_b;
    if (!active || k >= nzneg) {
        // thr <= 0: excluded pixels all have pn==0 => mask==0 => zero contribution.
        Lc_b = 1.0f - 2.0f * S[18] / (S[19] + S[20] + EPSF);
    } else {
        // -------- RARE exact path (not hit by bench data; correctness only) --------
        unsigned* h1 = histws + (size_t)b * NBIN;
        unsigned* c1 = chunkws + (size_t)b * NCHK;
        const float* pr6 = preds + ((size_t)b * NCH + 6) * PX;
        const int*   lb6 = labels + ((size_t)b * NCH + 6) * PX;
        const int*   mk  = mask + (size_t)b * PX;

        for (int j = tid; j < NBIN; j += NT) h1[j] = 0u;
        for (int j = tid; j < NCHK; j += NT) c1[j] = 0u;
        __syncthreads();
        for (int gg = tid; gg < PX; gg += NT) {
            float pnx = sigf(pr6[gg]) * (float)mk[gg];
            if (pnx < 0.5f) {
                unsigned bits = __float_as_uint(pnx);
                if (bits) {
                    atomicAdd(&h1[bits >> 16], 1u);
                    atomicAdd(&c1[bits >> 24], 1u);
                }
            }
        }
        __syncthreads();
        if (tid == 0) { atomicAdd(&h1[0], zc); atomicAdd(&c1[0], zc); }
        __syncthreads();

        __shared__ unsigned rb, rr, rb2, rr2;
        select2(c1, h1, k, &rb, &rr);
        float thrv;
        if (rb == 0u) {
            thrv = 0.0f;
        } else {
            unsigned hi = rb;
            for (int j = tid; j < NBIN; j += NT) h1[j] = 0u;
            for (int j = tid; j < NCHK; j += NT) c1[j] = 0u;
            __syncthreads();
            for (int gg = tid; gg < PX; gg += NT) {
                float pnx = sigf(pr6[gg]) * (float)mk[gg];
                if (pnx < 0.5f) {
                    unsigned bits = __float_as_uint(pnx);
                    if (bits && (bits >> 16) == hi) {
                        unsigned lo = bits & 0xFFFFu;
                        atomicAdd(&h1[lo], 1u);
                        atomicAdd(&c1[lo >> 8], 1u);
                    }
                }
            }
            __syncthreads();
            select2(c1, h1, rr, &rb2, &rr2);
            thrv = __uint_as_float((hi << 16) | rb2);
        }
        float a0 = 0.f, a1 = 0.f, a2 = 0.f;
        for (int gg = tid; gg < PX; gg += NT) {
            float m   = (float)mk[gg];
            float pnx = sigf(pr6[gg]) * m;
            if (pnx >= thrv) {
                float ln = (float)lb6[gg] * m;
                a0 += pnx * ln;
                a1 += pnx * pnx;
                a2 += ln;
            }
        }
        __shared__ float aR[4][3];
        wred3_f(a0, a1, a2);
        if (lane == 0) { aR[wid][0] = a0; aR[wid][1] = a1; aR[wid][2] = a2; }
        __syncthreads();
        float A0 = aR[0][0] + aR[1][0] + aR[2][0] + aR[3][0];
        float A1 = aR[0][1] + aR[1][1] + aR[2][1] + aR[3][1];
        float A2 = aR[0][2] + aR[1][2] + aR[2][2] + aR[3][2];
        Lc_b = 1.0f - 2.0f * A0 / (A1 + A2 + EPSF);
    }

    float ls_acc = 0.f;
    #pragma unroll
    for (int c = 0; c < 6; c++)
        ls_acc += (2.0f * S[c]) / (S[6 + c] + S[12 + c] + EPSF);
    float Ls_b = 1.0f - ls_acc * (1.0f / 6.0f);

    if (tid == 0) {
        lcls[b * 2]     = Lc_b;
        lcls[b * 2 + 1] = Ls_b;
    }

    // ---- 8-block ticket -> last block emits final losses ----
    __shared__ unsigned tick;
    if (tid == 0) {
        __threadfence();
        tick = atomicAdd(done, 1u);
    }
    __syncthreads();
    if (tick != (unsigned)(BS - 1)) return;
    __threadfence();

    float Lc = 0.f, Ls = 0.f;
    if (tid < BS) { Lc = lcls[tid * 2]; Ls = lcls[tid * 2 + 1]; }
    #pragma unroll
    for (int o = 4; o; o >>= 1) { Lc += __shfl_down(Lc, o); Ls += __shfl_down(Ls, o); }
    if (tid == 0) {
        float lc_m = Lc * (1.0f / (float)BS);
        float ls_m = Ls * (1.0f / (float)BS);
        out[0] = lc_m;
        out[1] = ls_m;
        out[2] = 0.7f * lc_m + 0.3f * ls_m;
    }
}

extern "C" void kernel_launch(void* const* d_in, const int* in_sizes, int n_in,
                              void* d_out, int out_size, void* d_ws, size_t ws_size,
                              hipStream_t stream) {
    const float* preds = (const float*)d_in[0];
    const int* labels  = (const int*)d_in[1];
    const int* mask    = (const int*)d_in[2];
    float* out = (float*)d_out;

    // workspace (nothing needs pre-zeroing)
    float*    psumA   = (float*)d_ws;                              // BS*3*GXM
    unsigned* ppos    = (unsigned*)(psumA + (size_t)BS * 3 * GXM); // BS*GXM
    unsigned* pzero   = ppos + BS * GXM;                           // BS*GXM
    float*    psumB   = (float*)(pzero + BS * GXM);                // BS*18*GXM
    unsigned* done    = (unsigned*)(psumB + (size_t)BS * 18 * GXM); // 1 (pad 8)
    float*    lcls    = (float*)(done + 8);                        // BS*2
    unsigned* histws  = (unsigned*)(lcls + BS * 2);                // BS*NBIN (rare)
    unsigned* chunkws = histws + (size_t)BS * NBIN;                // BS*NCHK (rare)

    hipLaunchKernelGGL(k_main, dim3(GXM, BS * 2), dim3(NT), 0, stream,
                       preds, labels, mask, psumA, ppos, pzero, psumB, done);

    hipLaunchKernelGGL(k_sel, dim3(BS), dim3(NT), 0, stream,
                       preds, labels, mask, psumA, psumB, ppos, pzero,
                       histws, chunkws, lcls, done, out);
}